// Round 17
// baseline (857.803 us; speedup 1.0000x reference)
//
#include <hip/hip_runtime.h>

typedef unsigned short u16;
typedef __attribute__((ext_vector_type(8))) short short8;
typedef __attribute__((ext_vector_type(4))) float f32x4;

#define SCALE_ 0.125f

struct __align__(8) U16x4 { u16 x, y, z, w; };

__device__ __forceinline__ u16 f2b(float f) {
  union { float f; unsigned u; } c; c.f = f;
  unsigned u = c.u;
  u += 0x7fffu + ((u >> 16) & 1u);
  return (u16)(u >> 16);
}

__device__ __forceinline__ void gload16(const void* g, void* l) {
  __builtin_amdgcn_global_load_lds((const __attribute__((address_space(1))) void*)g,
                                   (__attribute__((address_space(3))) void*)l,
                                   16, 0, 0);
}

// gelu(x) = x * sigmoid(1.595769...*(x + 0.044715 x^3))
__device__ __forceinline__ float gelu_t(float x) {
  float z = 1.5957691216057308f * (x + 0.044715f * x * x * x);
  return x / (1.0f + __expf(-z));
}

// ---------------- merged weight-cast/transpose + ctx cast ------------------
struct WcastDesc {
  const float* src[8];
  void* dst[8];
  int K[8];          // K==0 marks the flat-cast (ctx) segment
  int N[8];
  int ofs[9];
};

__global__ __launch_bounds__(256) void wcast_all(WcastDesc d) {
  __shared__ float t[32][33];
  const int bid = blockIdx.x;
  int i = 0;
  while (bid >= d.ofs[i + 1]) ++i;
  const int rb = bid - d.ofs[i];
  if (d.K[i] == 0) {
    const int idx = rb * 256 + threadIdx.x;
    const float4 v = ((const float4*)d.src[i])[idx];
    U16x4 o; o.x = f2b(v.x); o.y = f2b(v.y); o.z = f2b(v.z); o.w = f2b(v.w);
    ((U16x4*)d.dst[i])[idx] = o;
    return;
  }
  const float* W = d.src[i];
  u16* Wt = (u16*)d.dst[i];
  const int K = d.K[i], N = d.N[i];
  const int nb = N >> 5;
  const int k0 = (rb / nb) << 5;
  const int n0 = (rb % nb) << 5;
  const int tx = threadIdx.x & 31;
  const int ty = threadIdx.x >> 5;
#pragma unroll
  for (int r = 0; r < 32; r += 8) t[ty + r][tx] = W[(size_t)(k0 + ty + r) * N + n0 + tx];
  __syncthreads();
#pragma unroll
  for (int r = 0; r < 32; r += 8) Wt[(size_t)(n0 + ty + r) * K + k0 + tx] = f2b(t[tx][ty + r]);
}

// ---------------- m6 = silu(mod) @ W_mod + b_mod  (96-block K-split) -------
__global__ __launch_bounds__(256) void mod_gemm(const float* __restrict__ mod,
                                                const float* __restrict__ Wm,
                                                const float* __restrict__ bm,
                                                float* __restrict__ m6) {
  __shared__ float s[4096];
  __shared__ float red[4][4][64];
  for (int i = threadIdx.x; i < 4096; i += 256) {
    float x = mod[i];
    s[i] = x / (1.0f + __expf(-x));
  }
  __syncthreads();
  const int jc = threadIdx.x & 63;
  const int kq = threadIdx.x >> 6;
  const int j = blockIdx.x * 64 + jc;
  float a0 = 0.0f, a1 = 0.0f, a2 = 0.0f, a3 = 0.0f;
  const int c0 = kq * 256;
#pragma unroll 8
  for (int c = c0; c < c0 + 256; c++) {
    float w = Wm[(size_t)c * 6144 + j];
    a0 += s[c] * w;
    a1 += s[1024 + c] * w;
    a2 += s[2048 + c] * w;
    a3 += s[3072 + c] * w;
  }
  red[kq][0][jc] = a0; red[kq][1][jc] = a1; red[kq][2][jc] = a2; red[kq][3][jc] = a3;
  __syncthreads();
  if (kq == 0) {
    const float b = bm[j];
#pragma unroll
    for (int bb = 0; bb < 4; bb++) {
      float v = red[0][bb][jc] + red[1][bb][jc] + red[2][bb][jc] + red[3][bb][jc] + b;
      m6[bb * 6144 + j] = v;
    }
  }
}

// ---------------- LayerNorm (+ modulation or gamma/beta) -> bf16 -----------
__global__ __launch_bounds__(256) void ln_k(const float* __restrict__ x,
                                            u16* __restrict__ out,
                                            const float* __restrict__ g,
                                            const float* __restrict__ bb,
                                            int batch_stride, int add_one) {
  const int row = blockIdx.x;
  const int tid = threadIdx.x;
  const float4 v = ((const float4*)(x + (size_t)row * 1024))[tid];
  float s = v.x + v.y + v.z + v.w;
  float q = v.x * v.x + v.y * v.y + v.z * v.z + v.w * v.w;
#pragma unroll
  for (int m = 1; m < 64; m <<= 1) {
    s += __shfl_xor(s, m, 64);
    q += __shfl_xor(q, m, 64);
  }
  __shared__ float ps[4], pq[4];
  if ((tid & 63) == 0) { ps[tid >> 6] = s; pq[tid >> 6] = q; }
  __syncthreads();
  s = ps[0] + ps[1] + ps[2] + ps[3];
  q = pq[0] + pq[1] + pq[2] + pq[3];
  const float mean = s * (1.0f / 1024.0f);
  const float var = q * (1.0f / 1024.0f) - mean * mean;
  const float rstd = rsqrtf(var + 1e-6f);
  const int batch = row >> 12;
  const float4 gv = ((const float4*)(g + (size_t)batch * batch_stride))[tid];
  const float4 bv = ((const float4*)(bb + (size_t)batch * batch_stride))[tid];
  const float ao = add_one ? 1.0f : 0.0f;
  U16x4 o;
  o.x = f2b((v.x - mean) * rstd * (gv.x + ao) + bv.x);
  o.y = f2b((v.y - mean) * rstd * (gv.y + ao) + bv.y);
  o.z = f2b((v.z - mean) * rstd * (gv.z + ao) + bv.z);
  o.w = f2b((v.w - mean) * rstd * (gv.w + ao) + bv.w);
  ((U16x4*)(out + (size_t)row * 1024))[tid] = o;
}

// ---------------- small GEMM (kv only): 128x128 tile -----------------------
template <int EPI>
__global__ __launch_bounds__(256) void gemm_bt(const u16* __restrict__ A,
                                               const u16* __restrict__ Bt,
                                               const float* __restrict__ bias,
                                               void* outp, const float* res,
                                               const float* gate, int M, int N,
                                               int K, int gate_stride) {
  __shared__ __align__(16) u16 As[4096];
  __shared__ __align__(16) u16 Bs[4096];
  const int nb = N >> 7;
  const int bm = (blockIdx.x / nb) << 7;
  const int bn = (blockIdx.x % nb) << 7;
  const int tid = threadIdx.x;
  const int lane = tid & 63;
  const int wv = tid >> 6;
  const int wr = (wv >> 1) << 6;
  const int wc = (wv & 1) << 6;
  const int lrow = lane & 15;
  const int lk = lane >> 4;
  const int srow = tid >> 2;
  const int scol = (tid & 3) << 3;
  const u16* gA = A + (size_t)(bm + srow) * K + scol;
  const u16* gB = Bt + (size_t)(bn + srow) * K + scol;
  const size_t rskip = (size_t)64 * K;
  u16* lA = As + wv * 512;
  u16* lB = Bs + wv * 512;
  f32x4 acc[4][4] = {};
  for (int k0 = 0; k0 < K; k0 += 32) {
    gload16(gA + k0, lA);
    gload16(gA + k0 + rskip, lA + 2048);
    gload16(gB + k0, lB);
    gload16(gB + k0 + rskip, lB + 2048);
    __syncthreads();
    short8 a[4], b[4];
#pragma unroll
    for (int m = 0; m < 4; m++)
      a[m] = *(const short8*)(As + (wr + m * 16 + lrow) * 32 + lk * 8);
#pragma unroll
    for (int n = 0; n < 4; n++)
      b[n] = *(const short8*)(Bs + (wc + n * 16 + lrow) * 32 + lk * 8);
#pragma unroll
    for (int m = 0; m < 4; m++)
#pragma unroll
      for (int n = 0; n < 4; n++)
        acc[m][n] = __builtin_amdgcn_mfma_f32_16x16x32_bf16(a[m], b[n], acc[m][n], 0, 0, 0);
    __syncthreads();
  }
#pragma unroll
  for (int m = 0; m < 4; m++) {
    const int row0 = bm + wr + m * 16 + lk * 4;
#pragma unroll
    for (int n = 0; n < 4; n++) {
      const int col = bn + wc + n * 16 + lrow;
      const float bval = bias[col];
#pragma unroll
      for (int j = 0; j < 4; j++) {
        float v = acc[m][n][j] + bval;
        size_t idx = (size_t)(row0 + j) * N + col;
        ((u16*)outp)[idx] = f2b(v);
      }
    }
  }
}

// ============ 256x256 GEMM (r12 main loop + L2-friendly 2D XCD mapping) ====
// Best measured structure (r12/r15): 4 phases/K-tile, VM4+s_barrier at
// P2/P4 only, compiler-managed lgkm waits, T2 swizzle, 128 KiB dbuf LDS.
// Grid mapping: per-XCD chunk remapped to column-groups of G=4 so the 4 hot
// B panels (2 MB) stay L2-resident while A panels stream (each reused 4x
// consecutively). Bijective for nb in {4,12,16}.
template <int EPI>
__global__ __launch_bounds__(512, 2) void gemm8p(const u16* __restrict__ A,
                                                 const u16* __restrict__ Bt,
                                                 const float* __restrict__ bias,
                                                 void* outp, const float* res,
                                                 const float* gate, int M, int N,
                                                 int K, int gate_stride) {
  extern __shared__ char smem[];
  const int nb = N >> 8;
  const int nwg = (M >> 8) * nb;
  const int cpx = nwg >> 3;
  const int xcd = blockIdx.x & 7;
  const int j = blockIdx.x >> 3;             // [0,cpx)
  const int rows_per = cpx / nb;             // bm rows per XCD
  const int grp = j / (rows_per * 4);
  const int rem = j - grp * (rows_per * 4);
  const int r2 = rem >> 2;
  const int c2 = rem & 3;
  const int bm = (xcd * rows_per + r2) << 8;
  const int bn = (grp * 4 + c2) << 8;
  const int tid = threadIdx.x;
  const int lane = tid & 63;
  const int w = tid >> 6;
  const int wm = w >> 2;
  const int wn = w & 3;
  const int lrow = lane & 15;
  const int lk = lane >> 4;
  const int u = (lane & 7) ^ (lane >> 3);
  const int r_off = w * 16 + ((lane >> 3) << 1) + (u >> 2);
  const int c_off = (u & 3) << 3;
  const u16* gA = A + (size_t)(bm + r_off) * K + c_off;
  const u16* gB = Bt + (size_t)(bn + r_off) * K + c_off;
  const size_t l_skip = (size_t)128 * K;
  char* sA = smem;
  char* sB = smem + 65536;
  const int dsb = ((lrow >> 1) << 7) + (((((lrow & 1) << 2) + lk) ^ (lrow >> 1)) << 4);
  const int aQ = wm * 8192;
  const int bQ = wn * 4096;

  f32x4 acc[8][4] = {};
  short8 bq[4];
  short8 af[4];

#define SG_A(d, kh, tt)                                                         \
  { gload16(gA + (size_t)(tt) * 64 + (kh) * 32, sA + (d) * 32768 + (kh) * 16384 + w * 1024);            \
    gload16(gA + l_skip + (size_t)(tt) * 64 + (kh) * 32, sA + (d) * 32768 + (kh) * 16384 + (w + 8) * 1024); }
#define SG_B(d, kh, tt)                                                         \
  { gload16(gB + (size_t)(tt) * 64 + (kh) * 32, sB + (d) * 32768 + (kh) * 16384 + w * 1024);            \
    gload16(gB + l_skip + (size_t)(tt) * 64 + (kh) * 32, sB + (d) * 32768 + (kh) * 16384 + (w + 8) * 1024); }
#define RD_A(d, kh, mh)                                                         \
  _Pragma("unroll") for (int m = 0; m < 4; m++)                                 \
    af[m] = *(const short8*)(sA + (d) * 32768 + (kh) * 16384 + aQ + (mh) * 4096 + m * 1024 + dsb);
#define RD_B(d, kh)                                                             \
  _Pragma("unroll") for (int n = 0; n < 4; n++)                                 \
    bq[n] = *(const short8*)(sB + (d) * 32768 + (kh) * 16384 + bQ + n * 1024 + dsb);
#define MM(mh)                                                                  \
  _Pragma("unroll") for (int m = 0; m < 4; m++)                                 \
    _Pragma("unroll") for (int n = 0; n < 4; n++)                               \
      acc[(mh) * 4 + m][n] =                                                    \
          __builtin_amdgcn_mfma_f32_16x16x32_bf16(af[m], bq[n], acc[(mh) * 4 + m][n], 0, 0, 0);
#define SBAR0 __builtin_amdgcn_sched_barrier(0)
#define VM4   asm volatile("s_waitcnt vmcnt(4)" ::: "memory")

  // prologue: stage tile 0 (kh0 A, kh0 B, kh1 A, kh1 B); publish kh0
  SG_A(0, 0, 0); SG_B(0, 0, 0); SG_A(0, 1, 0); SG_B(0, 1, 0);
  SBAR0;
  VM4;
  __builtin_amdgcn_s_barrier();

  const int nt = K >> 6;
  for (int t = 0; t < nt; ++t) {
    const int d = t & 1;
    const int dn = d ^ 1;
    const int tn = (t + 1 < nt) ? t + 1 : t;
    { // P1: kh0/mh0 ; stage A(next,kh0)
      RD_A(d, 0, 0); RD_B(d, 0);
      SG_A(dn, 0, tn);
      __builtin_amdgcn_s_setprio(1);
      MM(0);
      __builtin_amdgcn_s_setprio(0);
      SBAR0;
    }
    { // P2: kh0/mh1 ; stage B(next,kh0); VM4+barrier publishes kh1(t)
      RD_A(d, 0, 1);
      SG_B(dn, 0, tn);
      SBAR0;
      VM4;
      __builtin_amdgcn_s_barrier();
      SBAR0;
      __builtin_amdgcn_s_setprio(1);
      MM(1);
      __builtin_amdgcn_s_setprio(0);
      SBAR0;
    }
    { // P3: kh1/mh0 ; stage A(next,kh1)
      RD_A(d, 1, 0); RD_B(d, 1);
      SG_A(dn, 1, tn);
      __builtin_amdgcn_s_setprio(1);
      MM(0);
      __builtin_amdgcn_s_setprio(0);
      SBAR0;
    }
    { // P4: kh1/mh1 ; stage B(next,kh1); VM4+barrier publishes kh0(t+1)
      RD_A(d, 1, 1);
      SG_B(dn, 1, tn);
      SBAR0;
      VM4;
      __builtin_amdgcn_s_barrier();
      SBAR0;
      __builtin_amdgcn_s_setprio(1);
      MM(1);
      __builtin_amdgcn_s_setprio(0);
      SBAR0;
    }
  }
  asm volatile("s_waitcnt vmcnt(0)" ::: "memory");
#undef SG_A
#undef SG_B
#undef RD_A
#undef RD_B
#undef MM
#undef SBAR0
#undef VM4

  // ---- vectorized epilogue: per-wave LDS transpose -> coalesced stores ----
  __syncthreads();
  float* eb = (float*)smem + (size_t)w * 1088;
  const float* grow = nullptr;
  if (EPI == 2 && gate) grow = gate + (size_t)(bm >> 12) * gate_stride;
  const int erow = lane >> 4;
  const int ecol = (lane & 15) << 2;
  const int colb = bn + wn * 64 + ecol;
  const float4 bv4 = *(const float4*)(bias + colb);
  float4 gv4 = make_float4(1.0f, 1.0f, 1.0f, 1.0f);
  if (EPI == 2 && grow) gv4 = *(const float4*)(grow + colb);
#pragma unroll
  for (int m = 0; m < 8; m++) {
#pragma unroll
    for (int n = 0; n < 4; n++)
#pragma unroll
      for (int j2 = 0; j2 < 4; j2++)
        eb[(lk * 4 + j2) * 68 + n * 16 + lrow] = acc[m][n][j2];
    const int row0 = bm + wm * 128 + m * 16 + erow;
#pragma unroll
    for (int i = 0; i < 4; i++) {
      const int row = row0 + 4 * i;
      float4 v = *(const float4*)(eb + (erow + 4 * i) * 68 + ecol);
      v.x += bv4.x; v.y += bv4.y; v.z += bv4.z; v.w += bv4.w;
      const size_t base = (size_t)row * N + colb;
      if (EPI == 0) {
        U16x4 o; o.x = f2b(v.x); o.y = f2b(v.y); o.z = f2b(v.z); o.w = f2b(v.w);
        *(U16x4*)((u16*)outp + base) = o;
      } else if (EPI == 1) {
        U16x4 o; o.x = f2b(gelu_t(v.x)); o.y = f2b(gelu_t(v.y));
        o.z = f2b(gelu_t(v.z)); o.w = f2b(gelu_t(v.w));
        *(U16x4*)((u16*)outp + base) = o;
      } else {
        const float4 r4 = *(const float4*)(res + base);
        float4 o;
        o.x = r4.x + gv4.x * v.x; o.y = r4.y + gv4.y * v.y;
        o.z = r4.z + gv4.z * v.z; o.w = r4.w + gv4.w * v.w;
        *(float4*)((float*)outp + base) = o;
      }
    }
  }
}

// ---------------- flash attention, 8 waves / 256 q-rows, K/V dbuf ----------
template <int MODE>
__global__ __launch_bounds__(512) void attn_k(const u16* __restrict__ QKV,
                                              const u16* __restrict__ Q2,
                                              const u16* __restrict__ KV2,
                                              u16* __restrict__ O) {
  __shared__ __align__(16) u16 Ks[2][4096];
  __shared__ __align__(16) u16 Vt[2][4096];
  __shared__ __align__(16) u16 Ps[16384];
  const int bid = blockIdx.x;
  const int tid = threadIdx.x;
  const int lane = tid & 63;
  const int wv = tid >> 6;
  const int lrow = lane & 15;
  const int lk = lane >> 4;
  const u16 *qp, *kp, *vp;
  int q_row0, q_stride, kv_row0, kv_stride, nkt, ocol;
  if (MODE == 0) {
    const int qt = bid & 1, h = (bid >> 1) & 15, w = (bid >> 5) & 7, b = bid >> 8;
    const int win = (b * 8 + w) * 512;
    q_row0 = win + qt * 256; q_stride = 3072;
    qp = QKV + h * 64;
    kp = QKV + 1024 + h * 64;
    vp = QKV + 2048 + h * 64;
    kv_row0 = win; kv_stride = 3072; nkt = 8;
    ocol = h * 64;
  } else {
    const int qt = bid & 15, h = (bid >> 4) & 15, b = bid >> 8;
    q_row0 = b * 4096 + qt * 256; q_stride = 1024;
    qp = Q2 + h * 64;
    kp = KV2 + h * 64;
    vp = KV2 + 1024 + h * 64;
    kv_row0 = b * 256; kv_stride = 2048; nkt = 4;
    ocol = h * 64;
  }
  const int qr = q_row0 + wv * 32;
  short8 qf[2][2];
#pragma unroll
  for (int m = 0; m < 2; m++)
#pragma unroll
    for (int kk = 0; kk < 2; kk++)
      qf[m][kk] = *(const short8*)(qp + (size_t)(qr + m * 16 + lrow) * q_stride + kk * 32 + lk * 8);
  f32x4 oa[2][4] = {};
  float lst[2][4];
#pragma unroll
  for (int m = 0; m < 2; m++)
#pragma unroll
    for (int j = 0; j < 4; j++) lst[m][j] = 0.0f;

  const int srow = tid >> 3;
  const int schk = tid & 7;
  {
    gload16(kp + (size_t)(kv_row0 + srow) * kv_stride + ((schk ^ (srow & 7)) << 3),
            Ks[0] + wv * 512);
    short8 vv = *(const short8*)(vp + (size_t)(kv_row0 + srow) * kv_stride + (schk << 3));
#pragma unroll
    for (int i = 0; i < 8; i++) {
      const int ii = (i + schk) & 7;
      const int dd = (schk << 3) + ii;
      Vt[0][dd * 64 + (((srow >> 3) ^ (dd & 7)) << 3) + (srow & 7)] = (u16)vv[ii];
    }
  }
  __syncthreads();

  u16* Pw = Ps + wv * 2048;
  for (int kt = 0; kt < nkt; kt++) {
    const int cur = kt & 1, nxt = cur ^ 1;
    const int have = (kt + 1 < nkt);
    short8 vv;
    if (have) {
      const int kvr1 = kv_row0 + (kt + 1) * 64;
      gload16(kp + (size_t)(kvr1 + srow) * kv_stride + ((schk ^ (srow & 7)) << 3),
              Ks[nxt] + wv * 512);
      vv = *(const short8*)(vp + (size_t)(kvr1 + srow) * kv_stride + (schk << 3));
    }
    f32x4 s[2][4] = {};
    __builtin_amdgcn_s_setprio(1);
#pragma unroll
    for (int n = 0; n < 4; n++)
#pragma unroll
      for (int kk = 0; kk < 2; kk++) {
        short8 kb = *(const short8*)(Ks[cur] + (n * 16 + lrow) * 64 + (((kk * 4 + lk) ^ (lrow & 7)) << 3));
        s[0][n] = __builtin_amdgcn_mfma_f32_16x16x32_bf16(qf[0][kk], kb, s[0][n], 0, 0, 0);
        s[1][n] = __builtin_amdgcn_mfma_f32_16x16x32_bf16(qf[1][kk], kb, s[1][n], 0, 0, 0);
      }
    __builtin_amdgcn_s_setprio(0);
    if (have) {
#pragma unroll
      for (int i = 0; i < 8; i++) {
        const int ii = (i + schk) & 7;
        const int dd = (schk << 3) + ii;
        Vt[nxt][dd * 64 + (((srow >> 3) ^ (dd & 7)) << 3) + (srow & 7)] = (u16)vv[ii];
      }
    }
#pragma unroll
    for (int m = 0; m < 2; m++)
#pragma unroll
      for (int j = 0; j < 4; j++) {
        const float p0 = __expf(s[m][0][j] * SCALE_);
        const float p1 = __expf(s[m][1][j] * SCALE_);
        const float p2 = __expf(s[m][2][j] * SCALE_);
        const float p3 = __expf(s[m][3][j] * SCALE_);
        lst[m][j] += p0 + p1 + p2 + p3;
        const int prow = m * 16 + lk * 4 + j;
        const int base = prow * 64;
        const int r7 = prow & 7;
        const int kl = lrow >> 3, k7 = lrow & 7;
        Pw[base + (((0 + kl) ^ r7) << 3) + k7] = f2b(p0);
        Pw[base + (((2 + kl) ^ r7) << 3) + k7] = f2b(p1);
        Pw[base + (((4 + kl) ^ r7) << 3) + k7] = f2b(p2);
        Pw[base + (((6 + kl) ^ r7) << 3) + k7] = f2b(p3);
      }
#pragma unroll
    for (int kk = 0; kk < 2; kk++) {
      const int sw = ((kk * 4 + lk) ^ (lrow & 7)) << 3;
      short8 pa0 = *(const short8*)(Pw + lrow * 64 + sw);
      short8 pa1 = *(const short8*)(Pw + (16 + lrow) * 64 + sw);
      __builtin_amdgcn_s_setprio(1);
#pragma unroll
      for (int dn = 0; dn < 4; dn++) {
        short8 vb = *(const short8*)(Vt[cur] + (dn * 16 + lrow) * 64 + sw);
        oa[0][dn] = __builtin_amdgcn_mfma_f32_16x16x32_bf16(pa0, vb, oa[0][dn], 0, 0, 0);
        oa[1][dn] = __builtin_amdgcn_mfma_f32_16x16x32_bf16(pa1, vb, oa[1][dn], 0, 0, 0);
      }
      __builtin_amdgcn_s_setprio(0);
    }
    __syncthreads();
  }
#pragma unroll
  for (int m = 0; m < 2; m++)
#pragma unroll
    for (int j = 0; j < 4; j++) {
      float rs = lst[m][j];
      rs += __shfl_xor(rs, 1, 64);
      rs += __shfl_xor(rs, 2, 64);
      rs += __shfl_xor(rs, 4, 64);
      rs += __shfl_xor(rs, 8, 64);
      const float inv = 1.0f / rs;
      const int orow = qr + m * 16 + lk * 4 + j;
#pragma unroll
      for (int dn = 0; dn < 4; dn++)
        O[(size_t)orow * 1024 + ocol + dn * 16 + lrow] = f2b(oa[m][dn][j] * inv);
    }
}

// ---------------------------------------------------------------------------
extern "C" void kernel_launch(void* const* d_in, const int* in_sizes, int n_in,
                              void* d_out, int out_size, void* d_ws, size_t ws_size,
                              hipStream_t stream) {
  (void)in_sizes; (void)n_in; (void)out_size; (void)ws_size;
  const float* x      = (const float*)d_in[0];
  const float* ctx    = (const float*)d_in[1];
  const float* mod    = (const float*)d_in[2];
  const float* W_mod  = (const float*)d_in[3];
  const float* b_mod  = (const float*)d_in[4];
  const float* gamma2 = (const float*)d_in[5];
  const float* beta2  = (const float*)d_in[6];
  const float* W_qkv  = (const float*)d_in[7];
  const float* b_qkv  = (const float*)d_in[8];
  const float* W_so   = (const float*)d_in[9];
  const float* b_so   = (const float*)d_in[10];
  const float* W_q    = (const float*)d_in[11];
  const float* b_q    = (const float*)d_in[12];
  const float* W_kv   = (const float*)d_in[13];
  const float* b_kv   = (const float*)d_in[14];
  const float* W_co   = (const float*)d_in[15];
  const float* b_co   = (const float*)d_in[16];
  const float* W_m1   = (const float*)d_in[17];
  const float* b_m1   = (const float*)d_in[18];
  const float* W_m2   = (const float*)d_in[19];
  const float* b_m2   = (const float*)d_in[20];

  char* ws = (char*)d_ws;
  u16*   wt_qkv = (u16*)(ws + 0);
  u16*   wt_so  = (u16*)(ws + 6291456);
  u16*   wt_q   = (u16*)(ws + 8388608);
  u16*   wt_kv  = (u16*)(ws + 10485760);
  u16*   wt_co  = (u16*)(ws + 14680064);
  u16*   wt_m1  = (u16*)(ws + 16777216);
  u16*   wt_m2  = (u16*)(ws + 25165824);
  float* m6     = (float*)(ws + 33554432);
  u16*   ctxb   = (u16*)(ws + 33652736);
  u16*   kvb    = (u16*)(ws + 35749888);
  u16*   bufH   = (u16*)(ws + 39944192);
  u16*   bufO   = (u16*)(ws + 73498624);
  u16*   bufA   = (u16*)(ws + 107053056);
  float* xb1    = (float*)(ws + 107053056 + 50331648);
  float* outp   = (float*)d_out;

  hipFuncSetAttribute(reinterpret_cast<const void*>(&gemm8p<0>),
                      hipFuncAttributeMaxDynamicSharedMemorySize, 131072);
  hipFuncSetAttribute(reinterpret_cast<const void*>(&gemm8p<1>),
                      hipFuncAttributeMaxDynamicSharedMemorySize, 131072);
  hipFuncSetAttribute(reinterpret_cast<const void*>(&gemm8p<2>),
                      hipFuncAttributeMaxDynamicSharedMemorySize, 131072);

  // merged weight casts + ctx cast (single launch)
  WcastDesc wd;
  wd.src[0] = W_qkv; wd.dst[0] = wt_qkv; wd.K[0] = 1024; wd.N[0] = 3072;
  wd.src[1] = W_so;  wd.dst[1] = wt_so;  wd.K[1] = 1024; wd.N[1] = 1024;
  wd.src[2] = W_q;   wd.dst[2] = wt_q;   wd.K[2] = 1024; wd.N[2] = 1024;
  wd.src[3] = W_kv;  wd.dst[3] = wt_kv;  wd.K[3] = 1024; wd.N[3] = 2048;
  wd.src[4] = W_co;  wd.dst[4] = wt_co;  wd.K[4] = 1024; wd.N[4] = 1024;
  wd.src[5] = W_m1;  wd.dst[5] = wt_m1;  wd.K[5] = 1024; wd.N[5] = 4096;
  wd.src[6] = W_m2;  wd.dst[6] = wt_m2;  wd.K[6] = 4096; wd.N[6] = 1024;
  wd.src[7] = ctx;   wd.dst[7] = ctxb;   wd.K[7] = 0;    wd.N[7] = 0;
  wd.ofs[0] = 0;     wd.ofs[1] = 3072;  wd.ofs[2] = 4096; wd.ofs[3] = 5120;
  wd.ofs[4] = 7168;  wd.ofs[5] = 8192;  wd.ofs[6] = 12288; wd.ofs[7] = 16384;
  wd.ofs[8] = 17408;
  wcast_all<<<17408, 256, 0, stream>>>(wd);

  // modulation (96-block K-split)
  mod_gemm<<<96, 256, 0, stream>>>(mod, W_mod, b_mod, m6);

  // MSA branch
  ln_k<<<16384, 256, 0, stream>>>(x, bufH, m6 + 1024, m6 + 0, 6144, 1);
  gemm8p<0><<<768, 512, 131072, stream>>>(bufH, wt_qkv, b_qkv, bufA, nullptr, nullptr, 16384, 3072, 1024, 0);
  attn_k<0><<<1024, 512, 0, stream>>>(bufA, nullptr, nullptr, bufO);
  gemm8p<2><<<256, 512, 131072, stream>>>(bufO, wt_so, b_so, xb1, x, m6 + 2048, 16384, 1024, 1024, 6144);

  // cross-attention branch
  ln_k<<<16384, 256, 0, stream>>>(xb1, bufH, gamma2, beta2, 0, 0);
  gemm8p<0><<<256, 512, 131072, stream>>>(bufH, wt_q, b_q, bufA, nullptr, nullptr, 16384, 1024, 1024, 0);
  gemm_bt<0><<<128, 256, 0, stream>>>(ctxb, wt_kv, b_kv, kvb, nullptr, nullptr, 1024, 2048, 1024, 0);
  attn_k<1><<<1024, 512, 0, stream>>>(nullptr, bufA, kvb, bufO);
  gemm8p<2><<<256, 512, 131072, stream>>>(bufO, wt_co, b_co, outp, xb1, nullptr, 16384, 1024, 1024, 0);

  // MLP branch
  ln_k<<<16384, 256, 0, stream>>>(outp, bufH, m6 + 4096, m6 + 3072, 6144, 1);
  gemm8p<1><<<1024, 512, 131072, stream>>>(bufH, wt_m1, b_m1, bufA, nullptr, nullptr, 16384, 4096, 1024, 0);
  gemm8p<2><<<256, 512, 131072, stream>>>(bufA, wt_m2, b_m2, outp, outp, m6 + 5120, 16384, 1024, 4096, 6144);
}

// Round 18
// 841.614 us; speedup vs baseline: 1.0192x; 1.0192x over previous
//
#include <hip/hip_runtime.h>

typedef unsigned short u16;
typedef __attribute__((ext_vector_type(8))) short short8;
typedef __attribute__((ext_vector_type(4))) float f32x4;

#define SCALE_ 0.125f

struct __align__(8) U16x4 { u16 x, y, z, w; };

__device__ __forceinline__ u16 f2b(float f) {
  union { float f; unsigned u; } c; c.f = f;
  unsigned u = c.u;
  u += 0x7fffu + ((u >> 16) & 1u);
  return (u16)(u >> 16);
}

__device__ __forceinline__ void gload16(const void* g, void* l) {
  __builtin_amdgcn_global_load_lds((const __attribute__((address_space(1))) void*)g,
                                   (__attribute__((address_space(3))) void*)l,
                                   16, 0, 0);
}

// gelu(x) = x * sigmoid(1.595769...*(x + 0.044715 x^3))
__device__ __forceinline__ float gelu_t(float x) {
  float z = 1.5957691216057308f * (x + 0.044715f * x * x * x);
  return x / (1.0f + __expf(-z));
}

// ---------------- merged weight-cast/transpose + ctx cast ------------------
struct WcastDesc {
  const float* src[8];
  void* dst[8];
  int K[8];          // K==0 marks the flat-cast (ctx) segment
  int N[8];
  int ofs[9];
};

__global__ __launch_bounds__(256) void wcast_all(WcastDesc d) {
  __shared__ float t[32][33];
  const int bid = blockIdx.x;
  int i = 0;
  while (bid >= d.ofs[i + 1]) ++i;
  const int rb = bid - d.ofs[i];
  if (d.K[i] == 0) {
    const int idx = rb * 256 + threadIdx.x;
    const float4 v = ((const float4*)d.src[i])[idx];
    U16x4 o; o.x = f2b(v.x); o.y = f2b(v.y); o.z = f2b(v.z); o.w = f2b(v.w);
    ((U16x4*)d.dst[i])[idx] = o;
    return;
  }
  const float* W = d.src[i];
  u16* Wt = (u16*)d.dst[i];
  const int K = d.K[i], N = d.N[i];
  const int nb = N >> 5;
  const int k0 = (rb / nb) << 5;
  const int n0 = (rb % nb) << 5;
  const int tx = threadIdx.x & 31;
  const int ty = threadIdx.x >> 5;
#pragma unroll
  for (int r = 0; r < 32; r += 8) t[ty + r][tx] = W[(size_t)(k0 + ty + r) * N + n0 + tx];
  __syncthreads();
#pragma unroll
  for (int r = 0; r < 32; r += 8) Wt[(size_t)(n0 + ty + r) * K + k0 + tx] = f2b(t[tx][ty + r]);
}

// ---------------- m6 = silu(mod) @ W_mod + b_mod  (96-block K-split) -------
__global__ __launch_bounds__(256) void mod_gemm(const float* __restrict__ mod,
                                                const float* __restrict__ Wm,
                                                const float* __restrict__ bm,
                                                float* __restrict__ m6) {
  __shared__ float s[4096];
  __shared__ float red[4][4][64];
  for (int i = threadIdx.x; i < 4096; i += 256) {
    float x = mod[i];
    s[i] = x / (1.0f + __expf(-x));
  }
  __syncthreads();
  const int jc = threadIdx.x & 63;
  const int kq = threadIdx.x >> 6;
  const int j = blockIdx.x * 64 + jc;
  float a0 = 0.0f, a1 = 0.0f, a2 = 0.0f, a3 = 0.0f;
  const int c0 = kq * 256;
#pragma unroll 8
  for (int c = c0; c < c0 + 256; c++) {
    float w = Wm[(size_t)c * 6144 + j];
    a0 += s[c] * w;
    a1 += s[1024 + c] * w;
    a2 += s[2048 + c] * w;
    a3 += s[3072 + c] * w;
  }
  red[kq][0][jc] = a0; red[kq][1][jc] = a1; red[kq][2][jc] = a2; red[kq][3][jc] = a3;
  __syncthreads();
  if (kq == 0) {
    const float b = bm[j];
#pragma unroll
    for (int bb = 0; bb < 4; bb++) {
      float v = red[0][bb][jc] + red[1][bb][jc] + red[2][bb][jc] + red[3][bb][jc] + b;
      m6[bb * 6144 + j] = v;
    }
  }
}

// ---------------- LayerNorm (+ modulation or gamma/beta) -> bf16 -----------
__global__ __launch_bounds__(256) void ln_k(const float* __restrict__ x,
                                            u16* __restrict__ out,
                                            const float* __restrict__ g,
                                            const float* __restrict__ bb,
                                            int batch_stride, int add_one) {
  const int row = blockIdx.x;
  const int tid = threadIdx.x;
  const float4 v = ((const float4*)(x + (size_t)row * 1024))[tid];
  float s = v.x + v.y + v.z + v.w;
  float q = v.x * v.x + v.y * v.y + v.z * v.z + v.w * v.w;
#pragma unroll
  for (int m = 1; m < 64; m <<= 1) {
    s += __shfl_xor(s, m, 64);
    q += __shfl_xor(q, m, 64);
  }
  __shared__ float ps[4], pq[4];
  if ((tid & 63) == 0) { ps[tid >> 6] = s; pq[tid >> 6] = q; }
  __syncthreads();
  s = ps[0] + ps[1] + ps[2] + ps[3];
  q = pq[0] + pq[1] + pq[2] + pq[3];
  const float mean = s * (1.0f / 1024.0f);
  const float var = q * (1.0f / 1024.0f) - mean * mean;
  const float rstd = rsqrtf(var + 1e-6f);
  const int batch = row >> 12;
  const float4 gv = ((const float4*)(g + (size_t)batch * batch_stride))[tid];
  const float4 bv = ((const float4*)(bb + (size_t)batch * batch_stride))[tid];
  const float ao = add_one ? 1.0f : 0.0f;
  U16x4 o;
  o.x = f2b((v.x - mean) * rstd * (gv.x + ao) + bv.x);
  o.y = f2b((v.y - mean) * rstd * (gv.y + ao) + bv.y);
  o.z = f2b((v.z - mean) * rstd * (gv.z + ao) + bv.z);
  o.w = f2b((v.w - mean) * rstd * (gv.w + ao) + bv.w);
  ((U16x4*)(out + (size_t)row * 1024))[tid] = o;
}

// ---------------- small GEMM (kv only): 128x128 tile -----------------------
template <int EPI>
__global__ __launch_bounds__(256) void gemm_bt(const u16* __restrict__ A,
                                               const u16* __restrict__ Bt,
                                               const float* __restrict__ bias,
                                               void* outp, const float* res,
                                               const float* gate, int M, int N,
                                               int K, int gate_stride) {
  __shared__ __align__(16) u16 As[4096];
  __shared__ __align__(16) u16 Bs[4096];
  const int nb = N >> 7;
  const int bm = (blockIdx.x / nb) << 7;
  const int bn = (blockIdx.x % nb) << 7;
  const int tid = threadIdx.x;
  const int lane = tid & 63;
  const int wv = tid >> 6;
  const int wr = (wv >> 1) << 6;
  const int wc = (wv & 1) << 6;
  const int lrow = lane & 15;
  const int lk = lane >> 4;
  const int srow = tid >> 2;
  const int scol = (tid & 3) << 3;
  const u16* gA = A + (size_t)(bm + srow) * K + scol;
  const u16* gB = Bt + (size_t)(bn + srow) * K + scol;
  const size_t rskip = (size_t)64 * K;
  u16* lA = As + wv * 512;
  u16* lB = Bs + wv * 512;
  f32x4 acc[4][4] = {};
  for (int k0 = 0; k0 < K; k0 += 32) {
    gload16(gA + k0, lA);
    gload16(gA + k0 + rskip, lA + 2048);
    gload16(gB + k0, lB);
    gload16(gB + k0 + rskip, lB + 2048);
    __syncthreads();
    short8 a[4], b[4];
#pragma unroll
    for (int m = 0; m < 4; m++)
      a[m] = *(const short8*)(As + (wr + m * 16 + lrow) * 32 + lk * 8);
#pragma unroll
    for (int n = 0; n < 4; n++)
      b[n] = *(const short8*)(Bs + (wc + n * 16 + lrow) * 32 + lk * 8);
#pragma unroll
    for (int m = 0; m < 4; m++)
#pragma unroll
      for (int n = 0; n < 4; n++)
        acc[m][n] = __builtin_amdgcn_mfma_f32_16x16x32_bf16(a[m], b[n], acc[m][n], 0, 0, 0);
    __syncthreads();
  }
#pragma unroll
  for (int m = 0; m < 4; m++) {
    const int row0 = bm + wr + m * 16 + lk * 4;
#pragma unroll
    for (int n = 0; n < 4; n++) {
      const int col = bn + wc + n * 16 + lrow;
      const float bval = bias[col];
#pragma unroll
      for (int j = 0; j < 4; j++) {
        float v = acc[m][n][j] + bval;
        size_t idx = (size_t)(row0 + j) * N + col;
        ((u16*)outp)[idx] = f2b(v);
      }
    }
  }
}

// ============ 256x256 GEMM (r12 main loop + LDS-transposed vector epilogue) =
// Best measured structure: 4 phases/K-tile, VM4+s_barrier at P2/P4 only,
// compiler-managed lgkm waits, T2 swizzle, 128 KiB dbuf LDS, linear XCD swz.
template <int EPI>
__global__ __launch_bounds__(512, 2) void gemm8p(const u16* __restrict__ A,
                                                 const u16* __restrict__ Bt,
                                                 const float* __restrict__ bias,
                                                 void* outp, const float* res,
                                                 const float* gate, int M, int N,
                                                 int K, int gate_stride) {
  extern __shared__ char smem[];
  const int nb = N >> 8;
  const int nwg = (M >> 8) * nb;
  const int cpx = nwg >> 3;
  const int wg = (blockIdx.x & 7) * cpx + (blockIdx.x >> 3);
  const int bm = (wg / nb) << 8;
  const int bn = (wg % nb) << 8;
  const int tid = threadIdx.x;
  const int lane = tid & 63;
  const int w = tid >> 6;
  const int wm = w >> 2;
  const int wn = w & 3;
  const int lrow = lane & 15;
  const int lk = lane >> 4;
  const int u = (lane & 7) ^ (lane >> 3);
  const int r_off = w * 16 + ((lane >> 3) << 1) + (u >> 2);
  const int c_off = (u & 3) << 3;
  const u16* gA = A + (size_t)(bm + r_off) * K + c_off;
  const u16* gB = Bt + (size_t)(bn + r_off) * K + c_off;
  const size_t l_skip = (size_t)128 * K;
  char* sA = smem;
  char* sB = smem + 65536;
  const int dsb = ((lrow >> 1) << 7) + (((((lrow & 1) << 2) + lk) ^ (lrow >> 1)) << 4);
  const int aQ = wm * 8192;
  const int bQ = wn * 4096;

  f32x4 acc[8][4] = {};
  short8 bq[4];
  short8 af[4];

#define SG_A(d, kh, tt)                                                         \
  { gload16(gA + (size_t)(tt) * 64 + (kh) * 32, sA + (d) * 32768 + (kh) * 16384 + w * 1024);            \
    gload16(gA + l_skip + (size_t)(tt) * 64 + (kh) * 32, sA + (d) * 32768 + (kh) * 16384 + (w + 8) * 1024); }
#define SG_B(d, kh, tt)                                                         \
  { gload16(gB + (size_t)(tt) * 64 + (kh) * 32, sB + (d) * 32768 + (kh) * 16384 + w * 1024);            \
    gload16(gB + l_skip + (size_t)(tt) * 64 + (kh) * 32, sB + (d) * 32768 + (kh) * 16384 + (w + 8) * 1024); }
#define RD_A(d, kh, mh)                                                         \
  _Pragma("unroll") for (int m = 0; m < 4; m++)                                 \
    af[m] = *(const short8*)(sA + (d) * 32768 + (kh) * 16384 + aQ + (mh) * 4096 + m * 1024 + dsb);
#define RD_B(d, kh)                                                             \
  _Pragma("unroll") for (int n = 0; n < 4; n++)                                 \
    bq[n] = *(const short8*)(sB + (d) * 32768 + (kh) * 16384 + bQ + n * 1024 + dsb);
#define MM(mh)                                                                  \
  _Pragma("unroll") for (int m = 0; m < 4; m++)                                 \
    _Pragma("unroll") for (int n = 0; n < 4; n++)                               \
      acc[(mh) * 4 + m][n] =                                                    \
          __builtin_amdgcn_mfma_f32_16x16x32_bf16(af[m], bq[n], acc[(mh) * 4 + m][n], 0, 0, 0);
#define SBAR0 __builtin_amdgcn_sched_barrier(0)
#define VM4   asm volatile("s_waitcnt vmcnt(4)" ::: "memory")

  // prologue: stage tile 0 (kh0 A, kh0 B, kh1 A, kh1 B); publish kh0
  SG_A(0, 0, 0); SG_B(0, 0, 0); SG_A(0, 1, 0); SG_B(0, 1, 0);
  SBAR0;
  VM4;
  __builtin_amdgcn_s_barrier();

  const int nt = K >> 6;
  for (int t = 0; t < nt; ++t) {
    const int d = t & 1;
    const int dn = d ^ 1;
    const int tn = (t + 1 < nt) ? t + 1 : t;
    { // P1: kh0/mh0 ; stage A(next,kh0)
      RD_A(d, 0, 0); RD_B(d, 0);
      SG_A(dn, 0, tn);
      __builtin_amdgcn_s_setprio(1);
      MM(0);
      __builtin_amdgcn_s_setprio(0);
      SBAR0;
    }
    { // P2: kh0/mh1 ; stage B(next,kh0); VM4+barrier publishes kh1(t)
      RD_A(d, 0, 1);
      SG_B(dn, 0, tn);
      SBAR0;
      VM4;
      __builtin_amdgcn_s_barrier();
      SBAR0;
      __builtin_amdgcn_s_setprio(1);
      MM(1);
      __builtin_amdgcn_s_setprio(0);
      SBAR0;
    }
    { // P3: kh1/mh0 ; stage A(next,kh1)
      RD_A(d, 1, 0); RD_B(d, 1);
      SG_A(dn, 1, tn);
      __builtin_amdgcn_s_setprio(1);
      MM(0);
      __builtin_amdgcn_s_setprio(0);
      SBAR0;
    }
    { // P4: kh1/mh1 ; stage B(next,kh1); VM4+barrier publishes kh0(t+1)
      RD_A(d, 1, 1);
      SG_B(dn, 1, tn);
      SBAR0;
      VM4;
      __builtin_amdgcn_s_barrier();
      SBAR0;
      __builtin_amdgcn_s_setprio(1);
      MM(1);
      __builtin_amdgcn_s_setprio(0);
      SBAR0;
    }
  }
  asm volatile("s_waitcnt vmcnt(0)" ::: "memory");
#undef SG_A
#undef SG_B
#undef RD_A
#undef RD_B
#undef MM
#undef SBAR0
#undef VM4

  // ---- vectorized epilogue: per-wave LDS transpose -> coalesced stores ----
  __syncthreads();
  float* eb = (float*)smem + (size_t)w * 1088;
  const float* grow = nullptr;
  if (EPI == 2 && gate) grow = gate + (size_t)(bm >> 12) * gate_stride;
  const int erow = lane >> 4;
  const int ecol = (lane & 15) << 2;
  const int colb = bn + wn * 64 + ecol;
  const float4 bv4 = *(const float4*)(bias + colb);
  float4 gv4 = make_float4(1.0f, 1.0f, 1.0f, 1.0f);
  if (EPI == 2 && grow) gv4 = *(const float4*)(grow + colb);
#pragma unroll
  for (int m = 0; m < 8; m++) {
#pragma unroll
    for (int n = 0; n < 4; n++)
#pragma unroll
      for (int j = 0; j < 4; j++)
        eb[(lk * 4 + j) * 68 + n * 16 + lrow] = acc[m][n][j];
    const int row0 = bm + wm * 128 + m * 16 + erow;
#pragma unroll
    for (int i = 0; i < 4; i++) {
      const int row = row0 + 4 * i;
      float4 v = *(const float4*)(eb + (erow + 4 * i) * 68 + ecol);
      v.x += bv4.x; v.y += bv4.y; v.z += bv4.z; v.w += bv4.w;
      const size_t base = (size_t)row * N + colb;
      if (EPI == 0) {
        U16x4 o; o.x = f2b(v.x); o.y = f2b(v.y); o.z = f2b(v.z); o.w = f2b(v.w);
        *(U16x4*)((u16*)outp + base) = o;
      } else if (EPI == 1) {
        U16x4 o; o.x = f2b(gelu_t(v.x)); o.y = f2b(gelu_t(v.y));
        o.z = f2b(gelu_t(v.z)); o.w = f2b(gelu_t(v.w));
        *(U16x4*)((u16*)outp + base) = o;
      } else {
        const float4 r4 = *(const float4*)(res + base);
        float4 o;
        o.x = r4.x + gv4.x * v.x; o.y = r4.y + gv4.y * v.y;
        o.z = r4.z + gv4.z * v.z; o.w = r4.w + gv4.w * v.w;
        *(float4*)((float*)outp + base) = o;
      }
    }
  }
}

// ---------------- flash attention, 8 waves / 256 q-rows, K/V dbuf ----------
template <int MODE>
__global__ __launch_bounds__(512) void attn_k(const u16* __restrict__ QKV,
                                              const u16* __restrict__ Q2,
                                              const u16* __restrict__ KV2,
                                              u16* __restrict__ O) {
  __shared__ __align__(16) u16 Ks[2][4096];
  __shared__ __align__(16) u16 Vt[2][4096];
  __shared__ __align__(16) u16 Ps[16384];
  const int bid = blockIdx.x;
  const int tid = threadIdx.x;
  const int lane = tid & 63;
  const int wv = tid >> 6;
  const int lrow = lane & 15;
  const int lk = lane >> 4;
  const u16 *qp, *kp, *vp;
  int q_row0, q_stride, kv_row0, kv_stride, nkt, ocol;
  if (MODE == 0) {
    const int qt = bid & 1, h = (bid >> 1) & 15, w = (bid >> 5) & 7, b = bid >> 8;
    const int win = (b * 8 + w) * 512;
    q_row0 = win + qt * 256; q_stride = 3072;
    qp = QKV + h * 64;
    kp = QKV + 1024 + h * 64;
    vp = QKV + 2048 + h * 64;
    kv_row0 = win; kv_stride = 3072; nkt = 8;
    ocol = h * 64;
  } else {
    const int qt = bid & 15, h = (bid >> 4) & 15, b = bid >> 8;
    q_row0 = b * 4096 + qt * 256; q_stride = 1024;
    qp = Q2 + h * 64;
    kp = KV2 + h * 64;
    vp = KV2 + 1024 + h * 64;
    kv_row0 = b * 256; kv_stride = 2048; nkt = 4;
    ocol = h * 64;
  }
  const int qr = q_row0 + wv * 32;
  short8 qf[2][2];
#pragma unroll
  for (int m = 0; m < 2; m++)
#pragma unroll
    for (int kk = 0; kk < 2; kk++)
      qf[m][kk] = *(const short8*)(qp + (size_t)(qr + m * 16 + lrow) * q_stride + kk * 32 + lk * 8);
  f32x4 oa[2][4] = {};
  float lst[2][4];
#pragma unroll
  for (int m = 0; m < 2; m++)
#pragma unroll
    for (int j = 0; j < 4; j++) lst[m][j] = 0.0f;

  const int srow = tid >> 3;
  const int schk = tid & 7;
  {
    gload16(kp + (size_t)(kv_row0 + srow) * kv_stride + ((schk ^ (srow & 7)) << 3),
            Ks[0] + wv * 512);
    short8 vv = *(const short8*)(vp + (size_t)(kv_row0 + srow) * kv_stride + (schk << 3));
#pragma unroll
    for (int i = 0; i < 8; i++) {
      const int ii = (i + schk) & 7;
      const int dd = (schk << 3) + ii;
      Vt[0][dd * 64 + (((srow >> 3) ^ (dd & 7)) << 3) + (srow & 7)] = (u16)vv[ii];
    }
  }
  __syncthreads();

  u16* Pw = Ps + wv * 2048;
  for (int kt = 0; kt < nkt; kt++) {
    const int cur = kt & 1, nxt = cur ^ 1;
    const int have = (kt + 1 < nkt);
    short8 vv;
    if (have) {
      const int kvr1 = kv_row0 + (kt + 1) * 64;
      gload16(kp + (size_t)(kvr1 + srow) * kv_stride + ((schk ^ (srow & 7)) << 3),
              Ks[nxt] + wv * 512);
      vv = *(const short8*)(vp + (size_t)(kvr1 + srow) * kv_stride + (schk << 3));
    }
    f32x4 s[2][4] = {};
    __builtin_amdgcn_s_setprio(1);
#pragma unroll
    for (int n = 0; n < 4; n++)
#pragma unroll
      for (int kk = 0; kk < 2; kk++) {
        short8 kb = *(const short8*)(Ks[cur] + (n * 16 + lrow) * 64 + (((kk * 4 + lk) ^ (lrow & 7)) << 3));
        s[0][n] = __builtin_amdgcn_mfma_f32_16x16x32_bf16(qf[0][kk], kb, s[0][n], 0, 0, 0);
        s[1][n] = __builtin_amdgcn_mfma_f32_16x16x32_bf16(qf[1][kk], kb, s[1][n], 0, 0, 0);
      }
    __builtin_amdgcn_s_setprio(0);
    if (have) {
#pragma unroll
      for (int i = 0; i < 8; i++) {
        const int ii = (i + schk) & 7;
        const int dd = (schk << 3) + ii;
        Vt[nxt][dd * 64 + (((srow >> 3) ^ (dd & 7)) << 3) + (srow & 7)] = (u16)vv[ii];
      }
    }
#pragma unroll
    for (int m = 0; m < 2; m++)
#pragma unroll
      for (int j = 0; j < 4; j++) {
        const float p0 = __expf(s[m][0][j] * SCALE_);
        const float p1 = __expf(s[m][1][j] * SCALE_);
        const float p2 = __expf(s[m][2][j] * SCALE_);
        const float p3 = __expf(s[m][3][j] * SCALE_);
        lst[m][j] += p0 + p1 + p2 + p3;
        const int prow = m * 16 + lk * 4 + j;
        const int base = prow * 64;
        const int r7 = prow & 7;
        const int kl = lrow >> 3, k7 = lrow & 7;
        Pw[base + (((0 + kl) ^ r7) << 3) + k7] = f2b(p0);
        Pw[base + (((2 + kl) ^ r7) << 3) + k7] = f2b(p1);
        Pw[base + (((4 + kl) ^ r7) << 3) + k7] = f2b(p2);
        Pw[base + (((6 + kl) ^ r7) << 3) + k7] = f2b(p3);
      }
#pragma unroll
    for (int kk = 0; kk < 2; kk++) {
      const int sw = ((kk * 4 + lk) ^ (lrow & 7)) << 3;
      short8 pa0 = *(const short8*)(Pw + lrow * 64 + sw);
      short8 pa1 = *(const short8*)(Pw + (16 + lrow) * 64 + sw);
      __builtin_amdgcn_s_setprio(1);
#pragma unroll
      for (int dn = 0; dn < 4; dn++) {
        short8 vb = *(const short8*)(Vt[cur] + (dn * 16 + lrow) * 64 + sw);
        oa[0][dn] = __builtin_amdgcn_mfma_f32_16x16x32_bf16(pa0, vb, oa[0][dn], 0, 0, 0);
        oa[1][dn] = __builtin_amdgcn_mfma_f32_16x16x32_bf16(pa1, vb, oa[1][dn], 0, 0, 0);
      }
      __builtin_amdgcn_s_setprio(0);
    }
    __syncthreads();
  }
#pragma unroll
  for (int m = 0; m < 2; m++)
#pragma unroll
    for (int j = 0; j < 4; j++) {
      float rs = lst[m][j];
      rs += __shfl_xor(rs, 1, 64);
      rs += __shfl_xor(rs, 2, 64);
      rs += __shfl_xor(rs, 4, 64);
      rs += __shfl_xor(rs, 8, 64);
      const float inv = 1.0f / rs;
      const int orow = qr + m * 16 + lk * 4 + j;
#pragma unroll
      for (int dn = 0; dn < 4; dn++)
        O[(size_t)orow * 1024 + ocol + dn * 16 + lrow] = f2b(oa[m][dn][j] * inv);
    }
}

// ---------------------------------------------------------------------------
extern "C" void kernel_launch(void* const* d_in, const int* in_sizes, int n_in,
                              void* d_out, int out_size, void* d_ws, size_t ws_size,
                              hipStream_t stream) {
  (void)in_sizes; (void)n_in; (void)out_size; (void)ws_size;
  const float* x      = (const float*)d_in[0];
  const float* ctx    = (const float*)d_in[1];
  const float* mod    = (const float*)d_in[2];
  const float* W_mod  = (const float*)d_in[3];
  const float* b_mod  = (const float*)d_in[4];
  const float* gamma2 = (const float*)d_in[5];
  const float* beta2  = (const float*)d_in[6];
  const float* W_qkv  = (const float*)d_in[7];
  const float* b_qkv  = (const float*)d_in[8];
  const float* W_so   = (const float*)d_in[9];
  const float* b_so   = (const float*)d_in[10];
  const float* W_q    = (const float*)d_in[11];
  const float* b_q    = (const float*)d_in[12];
  const float* W_kv   = (const float*)d_in[13];
  const float* b_kv   = (const float*)d_in[14];
  const float* W_co   = (const float*)d_in[15];
  const float* b_co   = (const float*)d_in[16];
  const float* W_m1   = (const float*)d_in[17];
  const float* b_m1   = (const float*)d_in[18];
  const float* W_m2   = (const float*)d_in[19];
  const float* b_m2   = (const float*)d_in[20];

  char* ws = (char*)d_ws;
  u16*   wt_qkv = (u16*)(ws + 0);
  u16*   wt_so  = (u16*)(ws + 6291456);
  u16*   wt_q   = (u16*)(ws + 8388608);
  u16*   wt_kv  = (u16*)(ws + 10485760);
  u16*   wt_co  = (u16*)(ws + 14680064);
  u16*   wt_m1  = (u16*)(ws + 16777216);
  u16*   wt_m2  = (u16*)(ws + 25165824);
  float* m6     = (float*)(ws + 33554432);
  u16*   ctxb   = (u16*)(ws + 33652736);
  u16*   kvb    = (u16*)(ws + 35749888);
  u16*   bufH   = (u16*)(ws + 39944192);
  u16*   bufO   = (u16*)(ws + 73498624);
  u16*   bufA   = (u16*)(ws + 107053056);
  float* xb1    = (float*)(ws + 107053056 + 50331648);
  float* outp   = (float*)d_out;

  hipFuncSetAttribute(reinterpret_cast<const void*>(&gemm8p<0>),
                      hipFuncAttributeMaxDynamicSharedMemorySize, 131072);
  hipFuncSetAttribute(reinterpret_cast<const void*>(&gemm8p<1>),
                      hipFuncAttributeMaxDynamicSharedMemorySize, 131072);
  hipFuncSetAttribute(reinterpret_cast<const void*>(&gemm8p<2>),
                      hipFuncAttributeMaxDynamicSharedMemorySize, 131072);

  // merged weight casts + ctx cast (single launch)
  WcastDesc wd;
  wd.src[0] = W_qkv; wd.dst[0] = wt_qkv; wd.K[0] = 1024; wd.N[0] = 3072;
  wd.src[1] = W_so;  wd.dst[1] = wt_so;  wd.K[1] = 1024; wd.N[1] = 1024;
  wd.src[2] = W_q;   wd.dst[2] = wt_q;   wd.K[2] = 1024; wd.N[2] = 1024;
  wd.src[3] = W_kv;  wd.dst[3] = wt_kv;  wd.K[3] = 1024; wd.N[3] = 2048;
  wd.src[4] = W_co;  wd.dst[4] = wt_co;  wd.K[4] = 1024; wd.N[4] = 1024;
  wd.src[5] = W_m1;  wd.dst[5] = wt_m1;  wd.K[5] = 1024; wd.N[5] = 4096;
  wd.src[6] = W_m2;  wd.dst[6] = wt_m2;  wd.K[6] = 4096; wd.N[6] = 1024;
  wd.src[7] = ctx;   wd.dst[7] = ctxb;   wd.K[7] = 0;    wd.N[7] = 0;
  wd.ofs[0] = 0;     wd.ofs[1] = 3072;  wd.ofs[2] = 4096; wd.ofs[3] = 5120;
  wd.ofs[4] = 7168;  wd.ofs[5] = 8192;  wd.ofs[6] = 12288; wd.ofs[7] = 16384;
  wd.ofs[8] = 17408;
  wcast_all<<<17408, 256, 0, stream>>>(wd);

  // modulation (96-block K-split)
  mod_gemm<<<96, 256, 0, stream>>>(mod, W_mod, b_mod, m6);

  // MSA branch
  ln_k<<<16384, 256, 0, stream>>>(x, bufH, m6 + 1024, m6 + 0, 6144, 1);
  gemm8p<0><<<768, 512, 131072, stream>>>(bufH, wt_qkv, b_qkv, bufA, nullptr, nullptr, 16384, 3072, 1024, 0);
  attn_k<0><<<1024, 512, 0, stream>>>(bufA, nullptr, nullptr, bufO);
  gemm8p<2><<<256, 512, 131072, stream>>>(bufO, wt_so, b_so, xb1, x, m6 + 2048, 16384, 1024, 1024, 6144);

  // cross-attention branch
  ln_k<<<16384, 256, 0, stream>>>(xb1, bufH, gamma2, beta2, 0, 0);
  gemm8p<0><<<256, 512, 131072, stream>>>(bufH, wt_q, b_q, bufA, nullptr, nullptr, 16384, 1024, 1024, 0);
  gemm_bt<0><<<128, 256, 0, stream>>>(ctxb, wt_kv, b_kv, kvb, nullptr, nullptr, 1024, 2048, 1024, 0);
  attn_k<1><<<1024, 512, 0, stream>>>(nullptr, bufA, kvb, bufO);
  gemm8p<2><<<256, 512, 131072, stream>>>(bufO, wt_co, b_co, outp, xb1, nullptr, 16384, 1024, 1024, 0);

  // MLP branch
  ln_k<<<16384, 256, 0, stream>>>(outp, bufH, m6 + 4096, m6 + 3072, 6144, 1);
  gemm8p<1><<<1024, 512, 131072, stream>>>(bufH, wt_m1, b_m1, bufA, nullptr, nullptr, 16384, 4096, 1024, 0);
  gemm8p<2><<<256, 512, 131072, stream>>>(bufA, wt_m2, b_m2, outp, outp, m6 + 5120, 16384, 1024, 4096, 6144);
}